// Round 9
// baseline (332.385 us; speedup 1.0000x reference)
//
#include <hip/hip_runtime.h>
#include <math.h>

#define NH 16
#define NB 64
#define DK 64
#define NE 32768
#define LDS_CAP 2048   // max edges whose scores live in LDS (bench segments ~512, max ~650)
#define CHUNK 48       // staged edges per chunk: 12KB = 3 x 1KB glds per wave
#define ROWB 256       // bytes per K/V row (DK*4)

typedef float vf4 __attribute__((ext_vector_type(4)));

// async global->LDS, width 16: per-lane global src, wave-uniform LDS base + lane*16
#define GLDS(g, l) \
  __builtin_amdgcn_global_load_lds((__attribute__((address_space(1))) const void*)(g), \
                                   (__attribute__((address_space(3))) void*)(l), 16, 0, 0)

// ws layout: [0..127] int bounds[NB+1] (padded to 512B).

// Kernel 0: segment bounds from sorted batch. bounds[b] = min{e : batch[e] >= b}.
__global__ void seg_bounds_kernel(const int* __restrict__ batch, int* __restrict__ bounds) {
    int e = blockIdx.x * 256 + threadIdx.x;
    if (e >= NE) return;
    int be = batch[e];
    if (e == 0) {
        for (int b = 0; b <= be; ++b) bounds[b] = 0;
    } else {
        int bp = batch[e - 1];
        for (int b = bp + 1; b <= be; ++b) bounds[b] = e;
    }
    if (e == NE - 1) {
        for (int b = be + 1; b <= NB; ++b) bounds[b] = NE;
    }
}

// Stage CHUNK rows [e0, e0+CHUNK) of a K/V head (gbase, bytes) into LDS buffer lb.
// Each wave issues 3 fire-and-forget 1KB global_load_lds — no VGPR destinations,
// so the register allocator cannot re-serialize the batch (R7/R8 lesson: VGPR=32
// proved register-level batching was collapsed; DMA staging can't be).
__device__ __forceinline__ void stage_rows(const char* __restrict__ gbase, float* lb,
                                           int e0, int wave, int lane) {
    const size_t head_max = (size_t)NE * ROWB - 16;   // clamp: stay inside this head
    #pragma unroll
    for (int i = 0; i < 3; ++i) {
        size_t off = (size_t)e0 * ROWB + (size_t)(wave * 3 + i) * 1024 + (size_t)lane * 16;
        if (off > head_max) off = head_max;           // per-lane src clamp; dest slot unused
        GLDS(gbase + off, (char*)lb + (wave * 3 + i) * 1024);
    }
}

// Fused kernel: one block per (h,b). 256 threads = 4 waves.
// Pass 1: double-buffered LDS staging of K chunks (async DMA), scores from LDS
//         via 16-lane-group dot + shuffle tree; scores -> ssc; online (m,l).
// Reduce: (m,l) -> block M, inv (V chunk 0 staged under the reduce).
// Pass 2: double-buffered LDS staging of V chunks; acc += p * V from LDS.
// Tail:   out store, then p-writes and complement zero-fill as trailing
//         fire-and-forget stores (no barrier after them -> never drained).
__global__ __launch_bounds__(256) void fused_kernel(
    const float* __restrict__ Q,      // [NH, NB, DK]
    const float* __restrict__ K,      // [NH, NE, DK]
    const float* __restrict__ V,      // [NH, NE, DK]
    const int*   __restrict__ bounds, // [NB+1]
    float* __restrict__ out,          // [NH, NB, DK]
    float* __restrict__ attn)         // [NH, NB, NE]
{
    const int task = blockIdx.x;      // h*NB + b
    const int h    = task >> 6;
    const int b    = task & (NB - 1);
    const int tid  = threadIdx.x;
    const int wave = tid >> 6;
    const int lane = tid & 63;
    const int j    = lane >> 4;       // edge offset within group of 4
    const int c    = lane & 15;       // float4 chunk of d

    const int start = bounds[b];
    const int end   = bounds[b + 1];
    const int S     = end - start;
    const bool single = (S <= LDS_CAP);
    const int nc    = (S + CHUNK - 1) / CHUNK;

    __shared__ __align__(16) float kbuf[2][CHUNK * DK];   // 24 KB staging (K, then V)
    __shared__ __align__(16) float ssc[LDS_CAP];          // 8 KB scores
    __shared__ __align__(16) float qs[DK];
    __shared__ float sm[4], sl[4];
    __shared__ float bM, bInv;
    __shared__ float red[4][16][4];

    if (tid < DK) qs[tid] = Q[((size_t)h * NB + b) * DK + tid];

    const char* gK = (const char*)K + (size_t)h * NE * ROWB;
    const char* gV = (const char*)V + (size_t)h * NE * ROWB;
    const float4* K4 = (const float4*)(K + (size_t)h * NE * DK);  // fallback only
    const float4* V4 = (const float4*)(V + (size_t)h * NE * DK);  // fallback only
    float* arow = attn + ((size_t)h * NB + b) * NE;

    // ---- Pass 1: staged K chunks ----
    if (nc > 0) stage_rows(gK, kbuf[0], start, wave, lane);
    __syncthreads();                           // publish qs + K chunk 0

    const float4 qc = ((const float4*)qs)[c];

    float m = -INFINITY, l = 0.f;
    int cur = 0;
    for (int t = 0; t < nc; ++t) {
        const int e0 = start + t * CHUNK;
        if (t + 1 < nc) stage_rows(gK, kbuf[cur ^ 1], e0 + CHUNK, wave, lane);
        const float4* kb4 = (const float4*)kbuf[cur];
        #pragma unroll
        for (int s = 0; s < 3; ++s) {
            const int r = s * 16 + wave * 4 + j;
            const int e = e0 + r;
            const bool valid = e < end;
            const float4 kv = kb4[r * 16 + c];
            float t2 = fmaf(kv.x, qc.x, fmaf(kv.y, qc.y, fmaf(kv.z, qc.z, kv.w * qc.w)));
            #pragma unroll
            for (int off = 1; off < 16; off <<= 1)
                t2 += __shfl_xor(t2, off);     // full dot, broadcast in 16-lane group
            if (valid) {
                if (single && c == 0) ssc[e - start] = t2;
                float nm = fmaxf(m, t2);
                l = l * __expf(m - nm) + __expf(t2 - nm);  // m=-inf first: 0 contribution
                m = nm;
            }
        }
        __syncthreads();                       // publish chunk t+1; WAR-protect kbuf[cur]
        cur ^= 1;
    }

    // ---- (m,l): merge j-groups, then waves ----
    #pragma unroll
    for (int off = 16; off < 64; off <<= 1) {
        float om = __shfl_xor(m, off);
        float ol = __shfl_xor(l, off);
        float nm = fmaxf(m, om);
        float t1 = (l  > 0.f) ? l  * __expf(m  - nm) : 0.f;
        float t2 = (ol > 0.f) ? ol * __expf(om - nm) : 0.f;
        m = nm; l = t1 + t2;
    }
    if (lane == 0) { sm[wave] = m; sl[wave] = l; }
    __syncthreads();                           // sm/sl visible; Pass-1 kbuf reads done

    // stage V chunk 0 under the reduce (kbuf free now; published by next sync)
    if (single && nc > 0) stage_rows(gV, kbuf[0], start, wave, lane);

    if (tid == 0) {
        float M = -INFINITY;
        #pragma unroll
        for (int w = 0; w < 4; ++w) M = fmaxf(M, sm[w]);
        float L = 0.f;
        #pragma unroll
        for (int w = 0; w < 4; ++w) L += (sl[w] > 0.f) ? sl[w] * __expf(sm[w] - M) : 0.f;
        bM = M; bInv = (L > 0.f) ? 1.f / L : 0.f;
    }
    __syncthreads();                           // publish bM/bInv + V chunk 0
    const float M   = bM;
    const float inv = bInv;

    float4 acc = make_float4(0.f, 0.f, 0.f, 0.f);

    if (single) {
        // ---- Pass 2: staged V chunks ----
        cur = 0;
        for (int t = 0; t < nc; ++t) {
            const int e0 = start + t * CHUNK;
            if (t + 1 < nc) stage_rows(gV, kbuf[cur ^ 1], e0 + CHUNK, wave, lane);
            const float4* vb4 = (const float4*)kbuf[cur];
            #pragma unroll
            for (int s = 0; s < 3; ++s) {
                const int r = s * 16 + wave * 4 + j;
                const int e = e0 + r;
                const bool valid = e < end;
                const int  si = valid ? (e - start) : 0;
                const float pe = valid ? __expf(ssc[si] - M) * inv : 0.f;
                const float4 v = vb4[r * 16 + c];
                acc.x = fmaf(pe, v.x, acc.x);
                acc.y = fmaf(pe, v.y, acc.y);
                acc.z = fmaf(pe, v.z, acc.z);
                acc.w = fmaf(pe, v.w, acc.w);
            }
            __syncthreads();
            cur ^= 1;
        }
    } else {
        // ---- Fallback (S > LDS_CAP, not hit by bench): chunked recompute, direct global ----
        for (int cs = start; cs < end; cs += LDS_CAP) {
            const int ce = (cs + LDS_CAP < end) ? cs + LDS_CAP : end;
            __syncthreads();
            for (int ek = cs + wave * 4; ek < ce; ek += 16) {
                const int  ej    = ek + j;
                const bool valid = ej < ce;
                const int  el    = valid ? ej : ce - 1;
                const float4 kv = K4[(size_t)el * (DK / 4) + c];
                float t2 = fmaf(kv.x, qc.x, fmaf(kv.y, qc.y, fmaf(kv.z, qc.z, kv.w * qc.w)));
                #pragma unroll
                for (int off = 1; off < 16; off <<= 1)
                    t2 += __shfl_xor(t2, off);
                if (valid && c == 0) ssc[el - cs] = t2;
            }
            __syncthreads();
            for (int ep = cs + tid; ep < ce; ep += 256)
                arow[ep] = __expf(ssc[ep - cs] - M) * inv;
            for (int ev = cs + wave * 4; ev < ce; ev += 16) {
                const int  ej    = ev + j;
                const bool valid = ej < ce;
                const int  el    = valid ? ej : ce - 1;
                const float pe = valid ? __expf(ssc[el - cs] - M) * inv : 0.f;
                const float4 v = V4[(size_t)el * (DK / 4) + c];
                acc.x = fmaf(pe, v.x, acc.x);
                acc.y = fmaf(pe, v.y, acc.y);
                acc.z = fmaf(pe, v.z, acc.z);
                acc.w = fmaf(pe, v.w, acc.w);
            }
        }
    }

    // ---- cross-wave out reduce ----
    #pragma unroll
    for (int off = 16; off < 64; off <<= 1) {
        acc.x += __shfl_xor(acc.x, off);
        acc.y += __shfl_xor(acc.y, off);
        acc.z += __shfl_xor(acc.z, off);
        acc.w += __shfl_xor(acc.w, off);
    }
    if (lane < 16) {
        red[wave][c][0] = acc.x;
        red[wave][c][1] = acc.y;
        red[wave][c][2] = acc.z;
        red[wave][c][3] = acc.w;
    }
    __syncthreads();
    if (tid < DK) {
        const int cc = tid >> 2, comp = tid & 3;
        float r = red[0][cc][comp] + red[1][cc][comp]
                + red[2][cc][comp] + red[3][cc][comp];
        out[((size_t)h * NB + b) * DK + tid] = r;
    }

    // ---- trailing fire-and-forget stores: p-writes + complement zero-fill ----
    if (single) {
        for (int ep = start + tid; ep < end; ep += 256)
            arow[ep] = __expf(ssc[ep - start] - M) * inv;
    }
    {
        vf4 z4 = (vf4)(0.f);
        vf4* arow4 = (vf4*)arow;
        const int zs = start >> 2;
        const int ze = (end + 3) >> 2;
        for (int i = tid; i < zs; i += 256) arow4[i] = z4;
        for (int i = ze + tid; i < NE / 4; i += 256) arow4[i] = z4;
        if (tid == 0) {
            for (int p = (zs << 2); p < start; ++p) arow[p] = 0.f;
        } else if (tid == 1) {
            for (int p = end; p < (ze << 2); ++p) arow[p] = 0.f;
        }
    }
}

extern "C" void kernel_launch(void* const* d_in, const int* in_sizes, int n_in,
                              void* d_out, int out_size, void* d_ws, size_t ws_size,
                              hipStream_t stream) {
    const float* Q     = (const float*)d_in[0];
    const float* K     = (const float*)d_in[1];
    const float* V     = (const float*)d_in[2];
    const int*   batch = (const int*)d_in[3];

    float* out  = (float*)d_out;                    // [NH,NB,DK]
    float* attn = out + (size_t)NH * NB * DK;       // [NH,NB,NE]

    int*   bounds = (int*)d_ws;                     // [NB+1]

    seg_bounds_kernel<<<NE / 256, 256, 0, stream>>>(batch, bounds);

    fused_kernel<<<NH * NB, 256, 0, stream>>>(Q, K, V, bounds, out, attn);
}